// Round 1
// baseline (4803.523 us; speedup 1.0000x reference)
//
#include <hip/hip_runtime.h>
#include <hip/hip_cooperative_groups.h>

namespace cg = cooperative_groups;

typedef __attribute__((ext_vector_type(8))) short short8;
typedef __attribute__((ext_vector_type(4))) float f32x4;

// Problem constants
#define S_LEN 256
#define BATCH 128
#define IN_DIM 1024
#define HID 512
#define G4 2048  // 4*HID

__device__ __forceinline__ unsigned short f32_bf16(float f) {
  unsigned int u = __float_as_uint(f);
  u = (u + 0x7FFFu + ((u >> 16) & 1u)) >> 16;  // RNE
  return (unsigned short)u;
}
__device__ __forceinline__ float bf16_f32(unsigned short h) {
  return __uint_as_float(((unsigned int)h) << 16);
}
__device__ __forceinline__ float sigm(float x) { return 1.0f / (1.0f + __expf(-x)); }
__device__ __forceinline__ float tanh_fast(float x) {
  return 1.0f - 2.0f / (__expf(2.0f * x) + 1.0f);
}

// ---------------- conversion kernels ----------------
__global__ void cvt_bf16(const float* __restrict__ src, unsigned short* __restrict__ dst, int n) {
  int i = (blockIdx.x * blockDim.x + threadIdx.x) * 4;
  if (i >= n) return;
  float4 v = *(const float4*)(src + i);
  ushort4 o;
  o.x = f32_bf16(v.x); o.y = f32_bf16(v.y); o.z = f32_bf16(v.z); o.w = f32_bf16(v.w);
  *(ushort4*)(dst + i) = o;
}

__global__ void bias_add(const float* __restrict__ a, const float* __restrict__ b,
                         float* __restrict__ o, int n) {
  int i = blockIdx.x * blockDim.x + threadIdx.x;
  if (i < n) o[i] = a[i] + b[i];
}

// ---------------- GEMM: Gx = x_bf16 @ w_ih_bf16^T + bias ----------------
__device__ __forceinline__ void gl_lds16(const void* g, void* l) {
  __builtin_amdgcn_global_load_lds(
      (const __attribute__((address_space(1))) unsigned int*)g,
      (__attribute__((address_space(3))) unsigned int*)l, 16, 0, 0);
}

template <int C_F32>
__global__ __launch_bounds__(256) void gemm_bias(
    const unsigned short* __restrict__ A,   // [32768][1024] bf16
    const unsigned short* __restrict__ Bw,  // [2048][1024] bf16
    const float* __restrict__ bias,         // [2048]
    void* __restrict__ Cout) {              // [32768][2048] fp32 or bf16
  __shared__ __align__(16) unsigned short As[128 * 32];
  __shared__ __align__(16) unsigned short Bs[128 * 32];
  const int tid = threadIdx.x;
  const int w = tid >> 6, l = tid & 63;
  const int wm = w & 1, wn = w >> 1;
  const int nt = blockIdx.x & 15, mt = blockIdx.x >> 4;

  f32x4 acc[4][4];
#pragma unroll
  for (int i = 0; i < 4; i++)
#pragma unroll
    for (int j = 0; j < 4; j++) acc[i][j] = f32x4{0.f, 0.f, 0.f, 0.f};

  for (int k0 = 0; k0 < 1024; k0 += 32) {
    __syncthreads();
#pragma unroll
    for (int jj = 0; jj < 2; jj++) {
      int cid = (w * 2 + jj) * 64 + l;       // 0..511 chunk id
      int row = cid >> 2, kc = cid & 3;      // 128 rows x 4 k-chunks of 8
      const unsigned short* ga = A + (size_t)(mt * 128 + row) * 1024 + k0 + kc * 8;
      gl_lds16(ga, As + (w * 2 + jj) * 512);
      const unsigned short* gb = Bw + (size_t)(nt * 128 + row) * 1024 + k0 + kc * 8;
      gl_lds16(gb, Bs + (w * 2 + jj) * 512);
    }
    __syncthreads();
    short8 a[4], b[4];
#pragma unroll
    for (int i = 0; i < 4; i++)
      a[i] = *(const short8*)&As[(wm * 64 + i * 16 + (l & 15)) * 32 + (l >> 4) * 8];
#pragma unroll
    for (int j = 0; j < 4; j++)
      b[j] = *(const short8*)&Bs[(wn * 64 + j * 16 + (l & 15)) * 32 + (l >> 4) * 8];
#pragma unroll
    for (int i = 0; i < 4; i++)
#pragma unroll
      for (int j = 0; j < 4; j++)
        acc[i][j] = __builtin_amdgcn_mfma_f32_16x16x32_bf16(a[i], b[j], acc[i][j], 0, 0, 0);
  }
  // epilogue: +bias, store
#pragma unroll
  for (int j = 0; j < 4; j++) {
    int cg = nt * 128 + wn * 64 + j * 16 + (l & 15);
    float bv = bias[cg];
#pragma unroll
    for (int i = 0; i < 4; i++) {
      int rbase = mt * 128 + wm * 64 + i * 16 + (l >> 4) * 4;
#pragma unroll
      for (int r = 0; r < 4; r++) {
        float v = acc[i][j][r] + bv;
        if (C_F32)
          ((float*)Cout)[(size_t)(rbase + r) * 2048 + cg] = v;
        else
          ((unsigned short*)Cout)[(size_t)(rbase + r) * 2048 + cg] = f32_bf16(v);
      }
    }
  }
}

// ---------------- persistent cooperative LSTM recurrence ----------------
// 128 blocks x 256 threads. block -> (m = batch tile of 16, s = hidden slice of 32)
// W_hh B-fragments live in registers for the whole kernel. c in registers.
// h double-buffered in global bf16. One grid.sync per step.
__global__ __launch_bounds__(256, 1) void lstm_rec(
    const unsigned short* __restrict__ whh,  // [2048][512] bf16
    const void* __restrict__ gx,             // [256][128][2048] fp32 or bf16 (bias folded in)
    int gx_f32,
    unsigned short* __restrict__ hbuf) {     // [2][128][512] bf16
  __shared__ __align__(16) unsigned short Hs[16][520];  // +8 pad: bank spread
  __shared__ __align__(16) float Gt[16][132];           // [batch][localcol n=j*4+g]
  cg::grid_group grid = cg::this_grid();

  const int tid = threadIdx.x;
  const int w = tid >> 6, l = tid & 63;
  const int m = blockIdx.x & 7;   // batch tile
  const int s = blockIdx.x >> 3;  // hidden slice (16 slices of 32)

  // ---- preload W_hh fragments into registers (constant over t) ----
  // local col n in [0,128): n = j*4+g, j in [0,32), g in [0,4)
  short8 bw[16][2];
#pragma unroll
  for (int u = 0; u < 2; u++) {
    int n = (2 * w + u) * 16 + (l & 15);
    int jn = n >> 2, g = n & 3;
    int R = g * 512 + s * 32 + jn;  // global gate row
    const unsigned short* base = whh + (size_t)R * 512 + ((l >> 4) * 8);
#pragma unroll
    for (int kk = 0; kk < 16; kk++) bw[kk][u] = *(const short8*)(base + kk * 32);
  }

  // this thread's two state elements: (bl0, jj) and (bl0+8, jj)
  const int jj = tid & 31;
  const int bl0 = tid >> 5;  // 0..7
  const int bl1 = bl0 + 8;
  float c0 = 0.f, c1 = 0.f;

  // zero-init h_buf[0] (ws is poisoned 0xAA)
  hbuf[(size_t)(m * 16 + bl0) * 512 + s * 32 + jj] = 0;
  hbuf[(size_t)(m * 16 + bl1) * 512 + s * 32 + jj] = 0;
  grid.sync();

  const float* gxf = (const float*)gx;
  const unsigned short* gxb = (const unsigned short*)gx;

  for (int t = 0; t < S_LEN; t++) {
    // ---- stage h tile [16][512] into LDS ----
    const unsigned short* hsrc = hbuf + (size_t)(t & 1) * (BATCH * HID);
#pragma unroll
    for (int it = 0; it < 4; it++) {
      int cchunk = it * 256 + tid;       // 1024 chunks of 8 bf16
      int row = cchunk >> 6, kc = cchunk & 63;
      uint4 v = *(const uint4*)(hsrc + (size_t)(m * 16 + row) * 512 + kc * 8);
      *(uint4*)&Hs[row][kc * 8] = v;
    }
    __syncthreads();

    // ---- gates tile [16 batches][32 cols per wave] via MFMA ----
    f32x4 acc0 = f32x4{0.f, 0.f, 0.f, 0.f};
    f32x4 acc1 = f32x4{0.f, 0.f, 0.f, 0.f};
#pragma unroll
    for (int kk = 0; kk < 16; kk++) {
      short8 a = *(const short8*)&Hs[l & 15][kk * 32 + (l >> 4) * 8];
      acc0 = __builtin_amdgcn_mfma_f32_16x16x32_bf16(a, bw[kk][0], acc0, 0, 0, 0);
      acc1 = __builtin_amdgcn_mfma_f32_16x16x32_bf16(a, bw[kk][1], acc1, 0, 0, 0);
    }
    // write gate tile to LDS (C-layout: row=(l>>4)*4+r is batch, col=lane&15)
#pragma unroll
    for (int r = 0; r < 4; r++) {
      Gt[(l >> 4) * 4 + r][(2 * w + 0) * 16 + (l & 15)] = acc0[r];
      Gt[(l >> 4) * 4 + r][(2 * w + 1) * 16 + (l & 15)] = acc1[r];
    }
    __syncthreads();

    // ---- pointwise update for the 2 owned (batch, hidden) pairs ----
    size_t gxrow = (size_t)(t * BATCH + m * 16) * G4 + s * 32 + jj;
    {
      float4 gv = *(const float4*)&Gt[bl0][jj * 4];
      size_t base = gxrow + (size_t)bl0 * G4;
      float p0, p1, p2, p3;
      if (gx_f32) {
        p0 = gxf[base]; p1 = gxf[base + 512]; p2 = gxf[base + 1024]; p3 = gxf[base + 1536];
      } else {
        p0 = bf16_f32(gxb[base]); p1 = bf16_f32(gxb[base + 512]);
        p2 = bf16_f32(gxb[base + 1024]); p3 = bf16_f32(gxb[base + 1536]);
      }
      float gi = sigm(gv.x + p0);
      float gf = sigm(gv.y + p1);
      float gg = tanh_fast(gv.z + p2);
      float go = sigm(gv.w + p3);
      c0 = gf * c0 + gi * gg;
      float hv = go * tanh_fast(c0);
      hbuf[(size_t)((t + 1) & 1) * (BATCH * HID) + (size_t)(m * 16 + bl0) * 512 + s * 32 + jj] =
          f32_bf16(hv);
    }
    {
      float4 gv = *(const float4*)&Gt[bl1][jj * 4];
      size_t base = gxrow + (size_t)bl1 * G4;
      float p0, p1, p2, p3;
      if (gx_f32) {
        p0 = gxf[base]; p1 = gxf[base + 512]; p2 = gxf[base + 1024]; p3 = gxf[base + 1536];
      } else {
        p0 = bf16_f32(gxb[base]); p1 = bf16_f32(gxb[base + 512]);
        p2 = bf16_f32(gxb[base + 1024]); p3 = bf16_f32(gxb[base + 1536]);
      }
      float gi = sigm(gv.x + p0);
      float gf = sigm(gv.y + p1);
      float gg = tanh_fast(gv.z + p2);
      float go = sigm(gv.w + p3);
      c1 = gf * c1 + gi * gg;
      float hv = go * tanh_fast(c1);
      hbuf[(size_t)((t + 1) & 1) * (BATCH * HID) + (size_t)(m * 16 + bl1) * 512 + s * 32 + jj] =
          f32_bf16(hv);
    }
    grid.sync();
  }
  // final h is in hbuf[0] (t=255 wrote buffer (255+1)&1 == 0)
}

// ---------------- final reduction: sum over h [128][512] ----------------
__global__ void reduce_sum(const unsigned short* __restrict__ h, float* __restrict__ out) {
  __shared__ float red[256];
  int tid = threadIdx.x;
  float s = 0.f;
  for (int i = tid * 8; i < BATCH * HID; i += 256 * 8) {
    uint4 v = *(const uint4*)(h + i);
    unsigned int q[4] = {v.x, v.y, v.z, v.w};
#pragma unroll
    for (int k = 0; k < 4; k++) {
      s += bf16_f32((unsigned short)(q[k] & 0xFFFFu));
      s += bf16_f32((unsigned short)(q[k] >> 16));
    }
  }
  red[tid] = s;
  __syncthreads();
  for (int off = 128; off > 0; off >>= 1) {
    if (tid < off) red[tid] += red[tid + off];
    __syncthreads();
  }
  if (tid == 0) out[0] = red[0];
}

// ---------------- launch ----------------
extern "C" void kernel_launch(void* const* d_in, const int* in_sizes, int n_in,
                              void* d_out, int out_size, void* d_ws, size_t ws_size,
                              hipStream_t stream) {
  const float* x = (const float*)d_in[0];     // [256][128][1024]
  const float* w_ih = (const float*)d_in[1];  // [2048][1024]
  const float* w_hh = (const float*)d_in[2];  // [2048][512]
  const float* b_ih = (const float*)d_in[3];  // [2048]
  const float* b_hh = (const float*)d_in[4];  // [2048]

  char* ws = (char*)d_ws;
  unsigned short* x_bf = (unsigned short*)(ws);                 // 67,108,864 B
  unsigned short* wih_bf = (unsigned short*)(ws + 67108864);    //  4,194,304 B
  unsigned short* whh_bf = (unsigned short*)(ws + 71303168);    //  2,097,152 B
  float* bias = (float*)(ws + 73400320);                        //      8,192 B
  unsigned short* hbuf = (unsigned short*)(ws + 73408512);      //    262,144 B
  void* gx = (void*)(ws + 73670656);                            // Gx

  const size_t need_f32 = 73670656ull + (size_t)S_LEN * BATCH * G4 * 4;  // ~342 MB
  int gx_f32 = (ws_size >= need_f32) ? 1 : 0;

  // conversions
  cvt_bf16<<<(33554432 / 4 + 255) / 256, 256, 0, stream>>>(x, x_bf, 33554432);
  cvt_bf16<<<(2097152 / 4 + 255) / 256, 256, 0, stream>>>(w_ih, wih_bf, 2097152);
  cvt_bf16<<<(1048576 / 4 + 255) / 256, 256, 0, stream>>>(w_hh, whh_bf, 1048576);
  bias_add<<<8, 256, 0, stream>>>(b_ih, b_hh, bias, 2048);

  // big input GEMM (bias folded)
  if (gx_f32)
    gemm_bias<1><<<4096, 256, 0, stream>>>(x_bf, wih_bf, bias, gx);
  else
    gemm_bias<0><<<4096, 256, 0, stream>>>(x_bf, wih_bf, bias, gx);

  // persistent cooperative recurrence
  void* args[] = {(void*)&whh_bf, (void*)&gx, (void*)&gx_f32, (void*)&hbuf};
  hipLaunchCooperativeKernel((const void*)lstm_rec, dim3(128), dim3(256), args, 0, stream);

  // scalar output
  reduce_sum<<<1, 256, 0, stream>>>(hbuf, (float*)d_out);
}

// Round 2
// 1958.519 us; speedup vs baseline: 2.4526x; 2.4526x over previous
//
#include <hip/hip_runtime.h>

typedef __attribute__((ext_vector_type(8))) short short8;
typedef __attribute__((ext_vector_type(4))) float f32x4;

// Problem constants
#define S_LEN 256
#define BATCH 128
#define IN_DIM 1024
#define HID 512
#define G4 2048  // 4*HID

__device__ __forceinline__ unsigned short f32_bf16(float f) {
  unsigned int u = __float_as_uint(f);
  u = (u + 0x7FFFu + ((u >> 16) & 1u)) >> 16;  // RNE
  return (unsigned short)u;
}
__device__ __forceinline__ float bf16_f32(unsigned short h) {
  return __uint_as_float(((unsigned int)h) << 16);
}
__device__ __forceinline__ float sigm(float x) { return 1.0f / (1.0f + __expf(-x)); }
__device__ __forceinline__ float tanh_fast(float x) {
  return 1.0f - 2.0f / (__expf(2.0f * x) + 1.0f);
}

// ---------------- conversion kernels ----------------
__global__ void cvt_bf16(const float* __restrict__ src, unsigned short* __restrict__ dst, int n) {
  int i = (blockIdx.x * blockDim.x + threadIdx.x) * 4;
  if (i >= n) return;
  float4 v = *(const float4*)(src + i);
  ushort4 o;
  o.x = f32_bf16(v.x); o.y = f32_bf16(v.y); o.z = f32_bf16(v.z); o.w = f32_bf16(v.w);
  *(ushort4*)(dst + i) = o;
}

__global__ void bias_add(const float* __restrict__ a, const float* __restrict__ b,
                         float* __restrict__ o, int n) {
  int i = blockIdx.x * blockDim.x + threadIdx.x;
  if (i < n) o[i] = a[i] + b[i];
}

// zero barrier state + h0 (ws is poisoned 0xAA before every launch)
__global__ void init_ws(unsigned* __restrict__ bar, unsigned short* __restrict__ hbuf) {
  int i = blockIdx.x * blockDim.x + threadIdx.x;
  if (i < 1024) bar[i] = 0;
  int nvec = BATCH * HID / 8;  // 8192 uint4 of bf16
  for (int k = i; k < nvec; k += gridDim.x * blockDim.x)
    ((uint4*)hbuf)[k] = make_uint4(0u, 0u, 0u, 0u);
}

// ---------------- GEMM: Gx = x_bf16 @ w_ih_bf16^T + bias ----------------
__device__ __forceinline__ void gl_lds16(const void* g, void* l) {
  __builtin_amdgcn_global_load_lds(
      (const __attribute__((address_space(1))) unsigned int*)g,
      (__attribute__((address_space(3))) unsigned int*)l, 16, 0, 0);
}

template <int C_F32>
__global__ __launch_bounds__(256) void gemm_bias(
    const unsigned short* __restrict__ A,   // [32768][1024] bf16
    const unsigned short* __restrict__ Bw,  // [2048][1024] bf16
    const float* __restrict__ bias,         // [2048]
    void* __restrict__ Cout) {              // [32768][2048] fp32 or bf16
  __shared__ __align__(16) unsigned short As[128 * 32];
  __shared__ __align__(16) unsigned short Bs[128 * 32];
  const int tid = threadIdx.x;
  const int w = tid >> 6, l = tid & 63;
  const int wm = w & 1, wn = w >> 1;
  const int nt = blockIdx.x & 15, mt = blockIdx.x >> 4;

  f32x4 acc[4][4];
#pragma unroll
  for (int i = 0; i < 4; i++)
#pragma unroll
    for (int j = 0; j < 4; j++) acc[i][j] = f32x4{0.f, 0.f, 0.f, 0.f};

  for (int k0 = 0; k0 < 1024; k0 += 32) {
    __syncthreads();
#pragma unroll
    for (int jj = 0; jj < 2; jj++) {
      int cid = (w * 2 + jj) * 64 + l;       // 0..511 chunk id
      int row = cid >> 2, kc = cid & 3;      // 128 rows x 4 k-chunks of 8
      const unsigned short* ga = A + (size_t)(mt * 128 + row) * 1024 + k0 + kc * 8;
      gl_lds16(ga, As + (w * 2 + jj) * 512);
      const unsigned short* gb = Bw + (size_t)(nt * 128 + row) * 1024 + k0 + kc * 8;
      gl_lds16(gb, Bs + (w * 2 + jj) * 512);
    }
    __syncthreads();
    short8 a[4], b[4];
#pragma unroll
    for (int i = 0; i < 4; i++)
      a[i] = *(const short8*)&As[(wm * 64 + i * 16 + (l & 15)) * 32 + (l >> 4) * 8];
#pragma unroll
    for (int j = 0; j < 4; j++)
      b[j] = *(const short8*)&Bs[(wn * 64 + j * 16 + (l & 15)) * 32 + (l >> 4) * 8];
#pragma unroll
    for (int i = 0; i < 4; i++)
#pragma unroll
      for (int j = 0; j < 4; j++)
        acc[i][j] = __builtin_amdgcn_mfma_f32_16x16x32_bf16(a[i], b[j], acc[i][j], 0, 0, 0);
  }
  // epilogue: +bias, store
#pragma unroll
  for (int j = 0; j < 4; j++) {
    int cg = nt * 128 + wn * 64 + j * 16 + (l & 15);
    float bv = bias[cg];
#pragma unroll
    for (int i = 0; i < 4; i++) {
      int rbase = mt * 128 + wm * 64 + i * 16 + (l >> 4) * 4;
#pragma unroll
      for (int r = 0; r < 4; r++) {
        float v = acc[i][j][r] + bv;
        if (C_F32)
          ((float*)Cout)[(size_t)(rbase + r) * 2048 + cg] = v;
        else
          ((unsigned short*)Cout)[(size_t)(rbase + r) * 2048 + cg] = f32_bf16(v);
      }
    }
  }
}

// ---------------- custom hierarchical grid barrier ----------------
// bar[0..255]: 8 arrival counters at bar[g*32] (128B apart). bar[512]: generation.
__device__ __forceinline__ void gsync(unsigned* __restrict__ cnt, unsigned* __restrict__ gen,
                                      int bid, unsigned step) {
  __syncthreads();  // all waves' h-stores issued+drained (vmcnt0 before s_barrier)
  const int tid = threadIdx.x;
  if (bid == 0) {
    if (tid < 64) {  // wave 0 of root block
      if (tid == 0) {
        __builtin_amdgcn_fence(__ATOMIC_RELEASE, "agent");  // writeback L2 (h visible)
        __hip_atomic_fetch_add(&cnt[0], 1u, __ATOMIC_RELAXED, __HIP_MEMORY_SCOPE_AGENT);
      }
      bool done;
      do {
        unsigned v = 0xFFFFFFFFu;
        if (tid < 8)
          v = __hip_atomic_load(&cnt[tid * 32], __ATOMIC_RELAXED, __HIP_MEMORY_SCOPE_AGENT);
        done = (v >= 16u * step);
        if (!done) __builtin_amdgcn_s_sleep(1);
      } while (!__all(done));
      if (tid == 0)
        __hip_atomic_store(gen, step, __ATOMIC_RELAXED, __HIP_MEMORY_SCOPE_AGENT);
    }
  } else {
    if (tid == 0) {
      __builtin_amdgcn_fence(__ATOMIC_RELEASE, "agent");
      __hip_atomic_fetch_add(&cnt[(bid >> 4) * 32], 1u, __ATOMIC_RELAXED,
                             __HIP_MEMORY_SCOPE_AGENT);
      while (__hip_atomic_load(gen, __ATOMIC_RELAXED, __HIP_MEMORY_SCOPE_AGENT) < step)
        __builtin_amdgcn_s_sleep(1);
    }
  }
  if (tid == 0) __builtin_amdgcn_fence(__ATOMIC_ACQUIRE, "agent");  // invalidate L1/L2
  __syncthreads();
}

// ---------------- persistent cooperative LSTM recurrence ----------------
__global__ __launch_bounds__(256, 1) void lstm_rec(
    const unsigned short* __restrict__ whh,  // [2048][512] bf16
    const void* __restrict__ gx,             // [256][128][2048] fp32 or bf16 (bias folded)
    int gx_f32,
    unsigned short* __restrict__ hbuf,       // [2][128][512] bf16
    unsigned* __restrict__ bar) {
  __shared__ __align__(16) unsigned short Hs[16][520];
  __shared__ __align__(16) float Gt[16][132];

  const int tid = threadIdx.x;
  const int w = tid >> 6, l = tid & 63;
  const int m = blockIdx.x & 7;   // batch tile
  const int s = blockIdx.x >> 3;  // hidden slice (16 slices of 32)
  unsigned* cnt = bar;
  unsigned* gen = bar + 512;

  // ---- preload W_hh fragments into registers (constant over t) ----
  short8 bw[16][2];
#pragma unroll
  for (int u = 0; u < 2; u++) {
    int n = (2 * w + u) * 16 + (l & 15);
    int jn = n >> 2, g = n & 3;
    int R = g * 512 + s * 32 + jn;  // global gate row
    const unsigned short* base = whh + (size_t)R * 512 + ((l >> 4) * 8);
#pragma unroll
    for (int kk = 0; kk < 16; kk++) bw[kk][u] = *(const short8*)(base + kk * 32);
  }

  const int jj = tid & 31;
  const int bl0 = tid >> 5;  // 0..7
  const int bl1 = bl0 + 8;
  float c0 = 0.f, c1 = 0.f;

  const float* gxf = (const float*)gx;
  const unsigned short* gxb = (const unsigned short*)gx;

  for (int t = 0; t < S_LEN; t++) {
    // ---- issue gx loads early (independent of h; latency hides under staging+MFMA) ----
    float p0[4], p1[4];
    {
      size_t gxrow = (size_t)(t * BATCH + m * 16) * G4 + s * 32 + jj;
      if (gx_f32) {
        const float* gp0 = gxf + gxrow + (size_t)bl0 * G4;
        const float* gp1 = gxf + gxrow + (size_t)bl1 * G4;
#pragma unroll
        for (int g = 0; g < 4; g++) { p0[g] = gp0[g * 512]; p1[g] = gp1[g * 512]; }
      } else {
        const unsigned short* gp0 = gxb + gxrow + (size_t)bl0 * G4;
        const unsigned short* gp1 = gxb + gxrow + (size_t)bl1 * G4;
#pragma unroll
        for (int g = 0; g < 4; g++) {
          p0[g] = bf16_f32(gp0[g * 512]);
          p1[g] = bf16_f32(gp1[g * 512]);
        }
      }
    }

    // ---- stage h tile [16][512] into LDS ----
    const unsigned short* hsrc = hbuf + (size_t)(t & 1) * (BATCH * HID);
#pragma unroll
    for (int it = 0; it < 4; it++) {
      int cchunk = it * 256 + tid;  // 1024 chunks of 8 bf16
      int row = cchunk >> 6, kc = cchunk & 63;
      uint4 v = *(const uint4*)(hsrc + (size_t)(m * 16 + row) * 512 + kc * 8);
      *(uint4*)&Hs[row][kc * 8] = v;
    }
    __syncthreads();

    // ---- gates tile [16 batches][32 cols per wave] via MFMA ----
    f32x4 acc0 = f32x4{0.f, 0.f, 0.f, 0.f};
    f32x4 acc1 = f32x4{0.f, 0.f, 0.f, 0.f};
#pragma unroll
    for (int kk = 0; kk < 16; kk++) {
      short8 a = *(const short8*)&Hs[l & 15][kk * 32 + (l >> 4) * 8];
      acc0 = __builtin_amdgcn_mfma_f32_16x16x32_bf16(a, bw[kk][0], acc0, 0, 0, 0);
      acc1 = __builtin_amdgcn_mfma_f32_16x16x32_bf16(a, bw[kk][1], acc1, 0, 0, 0);
    }
#pragma unroll
    for (int r = 0; r < 4; r++) {
      Gt[(l >> 4) * 4 + r][(2 * w + 0) * 16 + (l & 15)] = acc0[r];
      Gt[(l >> 4) * 4 + r][(2 * w + 1) * 16 + (l & 15)] = acc1[r];
    }
    __syncthreads();

    // ---- pointwise update for the 2 owned (batch, hidden) pairs ----
    unsigned short* hdst = hbuf + (size_t)((t + 1) & 1) * (BATCH * HID);
    {
      float4 gv = *(const float4*)&Gt[bl0][jj * 4];
      float gi = sigm(gv.x + p0[0]);
      float gf = sigm(gv.y + p0[1]);
      float gg = tanh_fast(gv.z + p0[2]);
      float go = sigm(gv.w + p0[3]);
      c0 = gf * c0 + gi * gg;
      float hv = go * tanh_fast(c0);
      hdst[(size_t)(m * 16 + bl0) * 512 + s * 32 + jj] = f32_bf16(hv);
    }
    {
      float4 gv = *(const float4*)&Gt[bl1][jj * 4];
      float gi = sigm(gv.x + p1[0]);
      float gf = sigm(gv.y + p1[1]);
      float gg = tanh_fast(gv.z + p1[2]);
      float go = sigm(gv.w + p1[3]);
      c1 = gf * c1 + gi * gg;
      float hv = go * tanh_fast(c1);
      hdst[(size_t)(m * 16 + bl1) * 512 + s * 32 + jj] = f32_bf16(hv);
    }

    if (t + 1 < S_LEN) gsync(cnt, gen, blockIdx.x, (unsigned)(t + 1));
  }
  // final h in hbuf[0]; kernel boundary gives coherence for reduce_sum
}

// ---------------- final reduction: sum over h [128][512] ----------------
__global__ void reduce_sum(const unsigned short* __restrict__ h, float* __restrict__ out) {
  __shared__ float red[256];
  int tid = threadIdx.x;
  float s = 0.f;
  for (int i = tid * 8; i < BATCH * HID; i += 256 * 8) {
    uint4 v = *(const uint4*)(h + i);
    unsigned int q[4] = {v.x, v.y, v.z, v.w};
#pragma unroll
    for (int k = 0; k < 4; k++) {
      s += bf16_f32((unsigned short)(q[k] & 0xFFFFu));
      s += bf16_f32((unsigned short)(q[k] >> 16));
    }
  }
  red[tid] = s;
  __syncthreads();
  for (int off = 128; off > 0; off >>= 1) {
    if (tid < off) red[tid] += red[tid + off];
    __syncthreads();
  }
  if (tid == 0) out[0] = red[0];
}

// ---------------- launch ----------------
extern "C" void kernel_launch(void* const* d_in, const int* in_sizes, int n_in,
                              void* d_out, int out_size, void* d_ws, size_t ws_size,
                              hipStream_t stream) {
  const float* x = (const float*)d_in[0];     // [256][128][1024]
  const float* w_ih = (const float*)d_in[1];  // [2048][1024]
  const float* w_hh = (const float*)d_in[2];  // [2048][512]
  const float* b_ih = (const float*)d_in[3];  // [2048]
  const float* b_hh = (const float*)d_in[4];  // [2048]

  char* ws = (char*)d_ws;
  unsigned short* x_bf = (unsigned short*)(ws);                 // 67,108,864 B
  unsigned short* wih_bf = (unsigned short*)(ws + 67108864);    //  4,194,304 B
  unsigned short* whh_bf = (unsigned short*)(ws + 71303168);    //  2,097,152 B
  float* bias = (float*)(ws + 73400320);                        //      8,192 B
  unsigned short* hbuf = (unsigned short*)(ws + 73408512);      //    262,144 B
  unsigned* bar = (unsigned*)(ws + 73670656);                   //      4,096 B
  void* gx = (void*)(ws + 73674752);                            // Gx

  const size_t need_f32 = 73674752ull + (size_t)S_LEN * BATCH * G4 * 4;  // ~342 MB
  int gx_f32 = (ws_size >= need_f32) ? 1 : 0;

  // conversions + barrier/h0 init
  cvt_bf16<<<(33554432 / 4 + 255) / 256, 256, 0, stream>>>(x, x_bf, 33554432);
  cvt_bf16<<<(2097152 / 4 + 255) / 256, 256, 0, stream>>>(w_ih, wih_bf, 2097152);
  cvt_bf16<<<(1048576 / 4 + 255) / 256, 256, 0, stream>>>(w_hh, whh_bf, 1048576);
  bias_add<<<8, 256, 0, stream>>>(b_ih, b_hh, bias, 2048);
  init_ws<<<32, 256, 0, stream>>>(bar, hbuf);

  // big input GEMM (bias folded)
  if (gx_f32)
    gemm_bias<1><<<4096, 256, 0, stream>>>(x_bf, wih_bf, bias, gx);
  else
    gemm_bias<0><<<4096, 256, 0, stream>>>(x_bf, wih_bf, bias, gx);

  // persistent cooperative recurrence (custom barrier inside)
  void* args[] = {(void*)&whh_bf, (void*)&gx, (void*)&gx_f32, (void*)&hbuf, (void*)&bar};
  hipLaunchCooperativeKernel((const void*)lstm_rec, dim3(128), dim3(256), args, 0, stream);

  // scalar output
  reduce_sum<<<1, 256, 0, stream>>>(hbuf, (float*)d_out);
}

// Round 3
// 1433.700 us; speedup vs baseline: 3.3504x; 1.3661x over previous
//
#include <hip/hip_runtime.h>

typedef __attribute__((ext_vector_type(8))) short short8;
typedef __attribute__((ext_vector_type(4))) float f32x4;

// Problem constants
#define S_LEN 256
#define BATCH 128
#define IN_DIM 1024
#define HID 512
#define G4 2048  // 4*HID

__device__ __forceinline__ unsigned short f32_bf16(float f) {
  unsigned int u = __float_as_uint(f);
  u = (u + 0x7FFFu + ((u >> 16) & 1u)) >> 16;  // RNE
  return (unsigned short)u;
}
__device__ __forceinline__ float bf16_f32(unsigned short h) {
  return __uint_as_float(((unsigned int)h) << 16);
}
__device__ __forceinline__ float sigm(float x) { return 1.0f / (1.0f + __expf(-x)); }
__device__ __forceinline__ float tanh_fast(float x) {
  return 1.0f - 2.0f / (__expf(2.0f * x) + 1.0f);
}

// ---------------- conversion kernels ----------------
__global__ void cvt_bf16(const float* __restrict__ src, unsigned short* __restrict__ dst, int n) {
  int i = (blockIdx.x * blockDim.x + threadIdx.x) * 4;
  if (i >= n) return;
  float4 v = *(const float4*)(src + i);
  ushort4 o;
  o.x = f32_bf16(v.x); o.y = f32_bf16(v.y); o.z = f32_bf16(v.z); o.w = f32_bf16(v.w);
  *(ushort4*)(dst + i) = o;
}

__global__ void bias_add(const float* __restrict__ a, const float* __restrict__ b,
                         float* __restrict__ o, int n) {
  int i = blockIdx.x * blockDim.x + threadIdx.x;
  if (i < n) o[i] = a[i] + b[i];
}

// zero barrier state + h0 (ws is poisoned 0xAA before every launch)
__global__ void init_ws(unsigned* __restrict__ bar, unsigned short* __restrict__ hbuf) {
  int i = blockIdx.x * blockDim.x + threadIdx.x;
  if (i < 1024) bar[i] = 0;
  int nvec = BATCH * HID / 8;  // h(0) buffer only
  for (int k = i; k < nvec; k += gridDim.x * blockDim.x)
    ((uint4*)hbuf)[k] = make_uint4(0u, 0u, 0u, 0u);
}

// ---------------- GEMM: Gx = x_bf16 @ w_ih_bf16^T + bias ----------------
__device__ __forceinline__ void gl_lds16(const void* g, void* l) {
  __builtin_amdgcn_global_load_lds(
      (const __attribute__((address_space(1))) unsigned int*)g,
      (__attribute__((address_space(3))) unsigned int*)l, 16, 0, 0);
}

template <int C_F32>
__global__ __launch_bounds__(256) void gemm_bias(
    const unsigned short* __restrict__ A,   // [32768][1024] bf16
    const unsigned short* __restrict__ Bw,  // [2048][1024] bf16
    const float* __restrict__ bias,         // [2048]
    void* __restrict__ Cout) {              // [32768][2048] fp32 or bf16
  __shared__ __align__(16) unsigned short As[128 * 32];
  __shared__ __align__(16) unsigned short Bs[128 * 32];
  const int tid = threadIdx.x;
  const int w = tid >> 6, l = tid & 63;
  const int wm = w & 1, wn = w >> 1;
  const int nt = blockIdx.x & 15, mt = blockIdx.x >> 4;

  f32x4 acc[4][4];
#pragma unroll
  for (int i = 0; i < 4; i++)
#pragma unroll
    for (int j = 0; j < 4; j++) acc[i][j] = f32x4{0.f, 0.f, 0.f, 0.f};

  for (int k0 = 0; k0 < 1024; k0 += 32) {
    __syncthreads();
#pragma unroll
    for (int jj = 0; jj < 2; jj++) {
      int cid = (w * 2 + jj) * 64 + l;       // 0..511 chunk id
      int row = cid >> 2, kc = cid & 3;      // 128 rows x 4 k-chunks of 8
      const unsigned short* ga = A + (size_t)(mt * 128 + row) * 1024 + k0 + kc * 8;
      gl_lds16(ga, As + (w * 2 + jj) * 512);
      const unsigned short* gb = Bw + (size_t)(nt * 128 + row) * 1024 + k0 + kc * 8;
      gl_lds16(gb, Bs + (w * 2 + jj) * 512);
    }
    __syncthreads();
    short8 a[4], b[4];
#pragma unroll
    for (int i = 0; i < 4; i++)
      a[i] = *(const short8*)&As[(wm * 64 + i * 16 + (l & 15)) * 32 + (l >> 4) * 8];
#pragma unroll
    for (int j = 0; j < 4; j++)
      b[j] = *(const short8*)&Bs[(wn * 64 + j * 16 + (l & 15)) * 32 + (l >> 4) * 8];
#pragma unroll
    for (int i = 0; i < 4; i++)
#pragma unroll
      for (int j = 0; j < 4; j++)
        acc[i][j] = __builtin_amdgcn_mfma_f32_16x16x32_bf16(a[i], b[j], acc[i][j], 0, 0, 0);
  }
  // epilogue: +bias, store
#pragma unroll
  for (int j = 0; j < 4; j++) {
    int cg = nt * 128 + wn * 64 + j * 16 + (l & 15);
    float bv = bias[cg];
#pragma unroll
    for (int i = 0; i < 4; i++) {
      int rbase = mt * 128 + wm * 64 + i * 16 + (l >> 4) * 4;
#pragma unroll
      for (int r = 0; r < 4; r++) {
        float v = acc[i][j][r] + bv;
        if (C_F32)
          ((float*)Cout)[(size_t)(rbase + r) * 2048 + cg] = v;
        else
          ((unsigned short*)Cout)[(size_t)(rbase + r) * 2048 + cg] = f32_bf16(v);
      }
    }
  }
}

// ---------------- persistent LSTM recurrence ----------------
// 8 independent groups (one per 16-batch tile m), 16 blocks each.
// h exchanged through LLC via agent-scope relaxed atomics (no cache fences).
// Per-group counter barrier: arrive = fetch_add after vmcnt drain; wait = spin.
__global__ __launch_bounds__(256, 1) void lstm_rec(
    const unsigned short* __restrict__ whh,  // [2048][512] bf16
    const void* __restrict__ gx,             // [256][128][2048] fp32 or bf16 (bias folded)
    int gx_f32,
    unsigned short* __restrict__ hbuf,       // [2][128][512] bf16
    unsigned* __restrict__ bar) {
  __shared__ __align__(16) unsigned short Hs[16][520];
  __shared__ __align__(16) float Gt[16][132];

  const int tid = threadIdx.x;
  const int w = tid >> 6, l = tid & 63;
  const int m = blockIdx.x & 7;   // batch tile -> group id (round-robin XCD for locality)
  const int s = blockIdx.x >> 3;  // hidden slice (16 slices of 32)
  unsigned* cnt = &bar[m * 32];   // one 128B line per group

  // ---- preload W_hh fragments into registers (constant over t) ----
  short8 bw[16][2];
#pragma unroll
  for (int u = 0; u < 2; u++) {
    int n = (2 * w + u) * 16 + (l & 15);
    int jn = n >> 2, g = n & 3;
    int R = g * 512 + s * 32 + jn;  // global gate row
    const unsigned short* base = whh + (size_t)R * 512 + ((l >> 4) * 8);
#pragma unroll
    for (int kk = 0; kk < 16; kk++) bw[kk][u] = *(const short8*)(base + kk * 32);
  }

  // pointwise ownership: 1 batch x 2 adjacent cols per thread -> 4B packed h store
  const int b = tid >> 4;        // 0..15 batch within tile
  const int p = tid & 15;        // col pair
  const int j0 = 2 * p;          // local hidden col (even)
  const int gb = m * 16 + b;     // global batch
  const int colg = s * 32 + j0;  // global hidden col (even)
  float c0 = 0.f, c1 = 0.f;

  const float* gxf = (const float*)gx;
  const unsigned short* gxb = (const unsigned short*)gx;
  unsigned* h32 = (unsigned*)hbuf;

  for (int t = 0; t < S_LEN; t++) {
    // ---- prefetch gx (independent of h; hides under spin+staging) ----
    float2 pg[4];
    {
      size_t base = (size_t)(t * BATCH + gb) * G4 + colg;
      if (gx_f32) {
#pragma unroll
        for (int g = 0; g < 4; g++) pg[g] = *(const float2*)(gxf + base + (size_t)g * 512);
      } else {
#pragma unroll
        for (int g = 0; g < 4; g++) {
          unsigned u = *(const unsigned*)(gxb + base + (size_t)g * 512);
          pg[g].x = bf16_f32((unsigned short)(u & 0xFFFFu));
          pg[g].y = bf16_f32((unsigned short)(u >> 16));
        }
      }
    }

    // ---- wait: group counter reaches 16*t (h(t) fully stored at LLC) ----
    if (t > 0 && tid == 0) {
      while (__hip_atomic_load(cnt, __ATOMIC_RELAXED, __HIP_MEMORY_SCOPE_AGENT) <
             16u * (unsigned)t) {}
    }
    __syncthreads();

    // ---- stage h(t) [16][512] bf16 into LDS via 8B LLC-direct loads ----
    const unsigned long long* hsrc =
        (const unsigned long long*)(hbuf + (size_t)(t & 1) * (BATCH * HID));
#pragma unroll
    for (int it = 0; it < 8; it++) {
      int c = it * 256 + tid;  // 2048 chunks of 8B (4 bf16)
      int row = c >> 7, kc = c & 127;
      unsigned long long v = __hip_atomic_load(&hsrc[(size_t)(m * 16 + row) * 128 + kc],
                                               __ATOMIC_RELAXED, __HIP_MEMORY_SCOPE_AGENT);
      *(unsigned long long*)&Hs[row][kc * 4] = v;
    }
    __syncthreads();

    // ---- gates tile [16 batches][32 cols per wave] via MFMA ----
    f32x4 acc0 = f32x4{0.f, 0.f, 0.f, 0.f};
    f32x4 acc1 = f32x4{0.f, 0.f, 0.f, 0.f};
#pragma unroll
    for (int kk = 0; kk < 16; kk++) {
      short8 a = *(const short8*)&Hs[l & 15][kk * 32 + (l >> 4) * 8];
      acc0 = __builtin_amdgcn_mfma_f32_16x16x32_bf16(a, bw[kk][0], acc0, 0, 0, 0);
      acc1 = __builtin_amdgcn_mfma_f32_16x16x32_bf16(a, bw[kk][1], acc1, 0, 0, 0);
    }
#pragma unroll
    for (int r = 0; r < 4; r++) {
      Gt[(l >> 4) * 4 + r][(2 * w + 0) * 16 + (l & 15)] = acc0[r];
      Gt[(l >> 4) * 4 + r][(2 * w + 1) * 16 + (l & 15)] = acc1[r];
    }
    __syncthreads();

    // ---- pointwise: batch b, cols j0/j0+1 ----
    float4 g0 = *(const float4*)&Gt[b][j0 * 4];      // gates i,f,g,o of col j0
    float4 g1 = *(const float4*)&Gt[b][j0 * 4 + 4];  // gates i,f,g,o of col j0+1
    float i0 = sigm(g0.x + pg[0].x), f0 = sigm(g0.y + pg[1].x);
    float gg0 = tanh_fast(g0.z + pg[2].x), o0 = sigm(g0.w + pg[3].x);
    c0 = f0 * c0 + i0 * gg0;
    float h0 = o0 * tanh_fast(c0);
    float i1 = sigm(g1.x + pg[0].y), f1 = sigm(g1.y + pg[1].y);
    float gg1 = tanh_fast(g1.z + pg[2].y), o1 = sigm(g1.w + pg[3].y);
    c1 = f1 * c1 + i1 * gg1;
    float h1 = o1 * tanh_fast(c1);
    unsigned hp = (unsigned)f32_bf16(h0) | ((unsigned)f32_bf16(h1) << 16);
    __hip_atomic_store(
        &h32[(size_t)((t + 1) & 1) * (BATCH * HID / 2) + (size_t)gb * 256 + (colg >> 1)], hp,
        __ATOMIC_RELAXED, __HIP_MEMORY_SCOPE_AGENT);

    // ---- arrive: all block's stores ack'd at LLC, then one RMW ----
    if (t + 1 < S_LEN) {
      asm volatile("s_waitcnt vmcnt(0)" ::: "memory");  // own stores complete
      __syncthreads();                                  // => all threads' stores complete
      if (tid == 0)
        __hip_atomic_fetch_add(cnt, 1u, __ATOMIC_RELAXED, __HIP_MEMORY_SCOPE_AGENT);
    }
  }
  // final h in hbuf[0]; kernel boundary gives coherence for reduce_sum
}

// ---------------- final reduction: sum over h [128][512] ----------------
__global__ void reduce_sum(const unsigned short* __restrict__ h, float* __restrict__ out) {
  __shared__ float red[256];
  int tid = threadIdx.x;
  float s = 0.f;
  for (int i = tid * 8; i < BATCH * HID; i += 256 * 8) {
    uint4 v = *(const uint4*)(h + i);
    unsigned int q[4] = {v.x, v.y, v.z, v.w};
#pragma unroll
    for (int k = 0; k < 4; k++) {
      s += bf16_f32((unsigned short)(q[k] & 0xFFFFu));
      s += bf16_f32((unsigned short)(q[k] >> 16));
    }
  }
  red[tid] = s;
  __syncthreads();
  for (int off = 128; off > 0; off >>= 1) {
    if (tid < off) red[tid] += red[tid + off];
    __syncthreads();
  }
  if (tid == 0) out[0] = red[0];
}

// ---------------- launch ----------------
extern "C" void kernel_launch(void* const* d_in, const int* in_sizes, int n_in,
                              void* d_out, int out_size, void* d_ws, size_t ws_size,
                              hipStream_t stream) {
  const float* x = (const float*)d_in[0];     // [256][128][1024]
  const float* w_ih = (const float*)d_in[1];  // [2048][1024]
  const float* w_hh = (const float*)d_in[2];  // [2048][512]
  const float* b_ih = (const float*)d_in[3];  // [2048]
  const float* b_hh = (const float*)d_in[4];  // [2048]

  char* ws = (char*)d_ws;
  unsigned short* x_bf = (unsigned short*)(ws);                 // 67,108,864 B
  unsigned short* wih_bf = (unsigned short*)(ws + 67108864);    //  4,194,304 B
  unsigned short* whh_bf = (unsigned short*)(ws + 71303168);    //  2,097,152 B
  float* bias = (float*)(ws + 73400320);                        //      8,192 B
  unsigned short* hbuf = (unsigned short*)(ws + 73408512);      //    262,144 B
  unsigned* bar = (unsigned*)(ws + 73670656);                   //      4,096 B
  void* gx = (void*)(ws + 73674752);                            // Gx

  const size_t need_f32 = 73674752ull + (size_t)S_LEN * BATCH * G4 * 4;  // ~342 MB
  int gx_f32 = (ws_size >= need_f32) ? 1 : 0;

  // conversions + barrier/h0 init
  cvt_bf16<<<(33554432 / 4 + 255) / 256, 256, 0, stream>>>(x, x_bf, 33554432);
  cvt_bf16<<<(2097152 / 4 + 255) / 256, 256, 0, stream>>>(w_ih, wih_bf, 2097152);
  cvt_bf16<<<(1048576 / 4 + 255) / 256, 256, 0, stream>>>(w_hh, whh_bf, 1048576);
  bias_add<<<8, 256, 0, stream>>>(b_ih, b_hh, bias, 2048);
  init_ws<<<32, 256, 0, stream>>>(bar, hbuf);

  // big input GEMM (bias folded)
  if (gx_f32)
    gemm_bias<1><<<4096, 256, 0, stream>>>(x_bf, wih_bf, bias, gx);
  else
    gemm_bias<0><<<4096, 256, 0, stream>>>(x_bf, wih_bf, bias, gx);

  // persistent recurrence (8 independent 16-block groups; cooperative launch
  // guarantees all blocks resident)
  void* args[] = {(void*)&whh_bf, (void*)&gx, (void*)&gx_f32, (void*)&hbuf, (void*)&bar};
  hipLaunchCooperativeKernel((const void*)lstm_rec, dim3(128), dim3(256), args, 0, stream);

  // scalar output
  reduce_sum<<<1, 256, 0, stream>>>(hbuf, (float*)d_out);
}